// Round 1
// baseline (106.115 us; speedup 1.0000x reference)
//
#include <hip/hip_runtime.h>

#define BS 4
#define NT 256
#define DM 64
#define NH 4

// ---------------------------------------------------------------------------
// Kernel 1: fused QV projection.
//  q_s[b][h][t][w] = (x[b,t,:] . wqv_w[h*64+w,:]   + wqv_b[h*64+w]) * wk[h,w]
//  vf [b][h][t][w] =  x[b,t,:] . wqv_w[(4+h)*64+w,:] + wqv_b[(4+h)*64+w]
// vb (rows 512..767) is dead in the reference -> skipped.
// 128 blocks x 8 tokens each, 256 threads.
// ---------------------------------------------------------------------------
__global__ __launch_bounds__(256) void k_proj(const float* __restrict__ x,
                                              const float* __restrict__ wk,
                                              const float* __restrict__ wqv_w,
                                              const float* __restrict__ wqv_b,
                                              float* __restrict__ q_s,
                                              float* __restrict__ vf)
{
    __shared__ float xs[8][DM];        // 2 KB
    __shared__ float wlds[512][17];    // 34.8 KB, +1 pad -> 2-way banks (free)

    const int tid  = threadIdx.x;
    const int tok0 = blockIdx.x * 8;   // global token base

    // load 8 x-rows (512 floats), coalesced
    for (int i = tid; i < 8 * DM; i += 256)
        xs[i >> 6][i & 63] = x[tok0 * DM + i];

    float acc[8][2];
#pragma unroll
    for (int t = 0; t < 8; ++t) { acc[t][0] = 0.f; acc[t][1] = 0.f; }

    const int r = tid;                 // output row in [0,256); also handles r+256

    for (int cc = 0; cc < 4; ++cc) {
        __syncthreads();
        // stage wqv_w[0..511][cc*16 .. cc*16+15]  (8192 floats, float4 loads)
        const int c0 = cc * 16;
        for (int i = tid; i < 512 * 4; i += 256) {
            const int row = i >> 2, c4 = (i & 3) * 4;
            const float4 v = *reinterpret_cast<const float4*>(&wqv_w[row * DM + c0 + c4]);
            wlds[row][c4 + 0] = v.x;
            wlds[row][c4 + 1] = v.y;
            wlds[row][c4 + 2] = v.z;
            wlds[row][c4 + 3] = v.w;
        }
        __syncthreads();
#pragma unroll
        for (int c = 0; c < 16; ++c) {
            const float wa = wlds[r][c];
            const float wb = wlds[r + 256][c];
            const int cg = c0 + c;
#pragma unroll
            for (int t = 0; t < 8; ++t) {
                acc[t][0] += xs[t][cg] * wa;
                acc[t][1] += xs[t][cg] * wb;
            }
        }
    }

    const int h = r >> 6, w = r & 63;
    const float ba  = wqv_b[r];
    const float bb  = wqv_b[r + 256];
    const float wkv = wk[h * DM + w];
#pragma unroll
    for (int t = 0; t < 8; ++t) {
        const int g = tok0 + t;
        const int b = g >> 8, tt = g & 255;
        q_s[(((b * NH) + h) * NT + tt) * DM + w] = (acc[t][0] + ba) * wkv;
        vf [(((b * NH) + h) * NT + tt) * DM + w] =  acc[t][1] + bb;
    }
}

// ---------------------------------------------------------------------------
// Kernel 2: L1-distance attention per (b,h), 16 queries per block.
//  dist[s,d] = sum_w |q_s[d,w] - x[s,w]*wk[h,w]| / 8
//  af = softmax over s of -huber(dist); bf[d,w] = sum_s af[s,d]*vf[s,w]
// grid (16 qtiles, 16 bh), 256 threads. 2 queries/thread in registers.
// ---------------------------------------------------------------------------
__global__ __launch_bounds__(256) void k_attn(const float* __restrict__ x,
                                              const float* __restrict__ wk,
                                              const float* __restrict__ q_s,
                                              const float* __restrict__ vf,
                                              float* __restrict__ bf)
{
    __shared__ float ks[64][66];       // 16.9 KB, pad 66 -> 2-way (free)
    __shared__ float af_lds[16][NT];   // 16 KB
    __shared__ float vfs[64][68];      // 17.4 KB, pad 68 keeps 16B align

    const int tid = threadIdx.x;
    const int qt  = blockIdx.x;        // 0..15 query tile
    const int bh  = blockIdx.y;        // 0..15
    const int b   = bh >> 2, h = bh & 3;
    const int qg  = tid >> 5;          // 0..7  (2 queries each)
    const int kg  = tid & 31;          // 0..31 (key lane)

    // ---- load 2 queries into registers (broadcast across the 32 kg lanes) --
    float q0[DM], q1[DM];
    const float* qbase = q_s + ((b * NH + h) * NT + qt * 16) * DM;
    {
        const float4* p0 = reinterpret_cast<const float4*>(qbase + (qg * 2 + 0) * DM);
        const float4* p1 = reinterpret_cast<const float4*>(qbase + (qg * 2 + 1) * DM);
#pragma unroll
        for (int i = 0; i < 16; ++i) {
            const float4 a = p0[i], c = p1[i];
            q0[4*i+0] = a.x; q0[4*i+1] = a.y; q0[4*i+2] = a.z; q0[4*i+3] = a.w;
            q1[4*i+0] = c.x; q1[4*i+1] = c.y; q1[4*i+2] = c.z; q1[4*i+3] = c.w;
        }
    }

    // ---- distance accumulation over 4 chunks of 64 keys ----
    float dacc[2][8];
#pragma unroll
    for (int j = 0; j < 8; ++j) { dacc[0][j] = 0.f; dacc[1][j] = 0.f; }

    for (int cc = 0; cc < 4; ++cc) {
        __syncthreads();
        // stage ks[r][c] = x[b][cc*64+r][c] * wk[h][c]   (4096 floats)
        {
            const int row = tid >> 2;
            const int c0  = (tid & 3) * 16;
            const float* xp = x + ((b * NT) + cc * 64 + row) * DM + c0;
#pragma unroll
            for (int i = 0; i < 4; ++i) {
                const float4 v  = *reinterpret_cast<const float4*>(xp + i * 4);
                const float4 wv = *reinterpret_cast<const float4*>(wk + h * DM + c0 + i * 4);
                ks[row][c0 + i*4 + 0] = v.x * wv.x;
                ks[row][c0 + i*4 + 1] = v.y * wv.y;
                ks[row][c0 + i*4 + 2] = v.z * wv.z;
                ks[row][c0 + i*4 + 3] = v.w * wv.w;
            }
        }
        __syncthreads();
#pragma unroll
        for (int k2 = 0; k2 < 2; ++k2) {
            const int kr = kg + 32 * k2;
            float d0 = 0.f, d1 = 0.f;
#pragma unroll
            for (int c = 0; c < 64; ++c) {
                const float kv = ks[kr][c];
                d0 += fabsf(q0[c] - kv);
                d1 += fabsf(q1[c] - kv);
            }
            dacc[0][cc * 2 + k2] = d0;
            dacc[1][cc * 2 + k2] = d1;
        }
    }

    // ---- huber + softmax over 256 keys (distributed over 32 lanes x 8) ----
    const float delta = 0.2f;
    float aa[2][8];
    float m0 = -1e30f, m1 = -1e30f;
#pragma unroll
    for (int j = 0; j < 8; ++j) {
        float d = dacc[0][j] * 0.125f;
        float hb = (d < delta) ? 0.5f * d * d : delta * (d - 0.5f * delta);
        aa[0][j] = -hb; m0 = fmaxf(m0, -hb);
        d = dacc[1][j] * 0.125f;
        hb = (d < delta) ? 0.5f * d * d : delta * (d - 0.5f * delta);
        aa[1][j] = -hb; m1 = fmaxf(m1, -hb);
    }
#pragma unroll
    for (int mask = 1; mask < 32; mask <<= 1) {
        m0 = fmaxf(m0, __shfl_xor(m0, mask, 32));
        m1 = fmaxf(m1, __shfl_xor(m1, mask, 32));
    }
    float s0 = 0.f, s1 = 0.f;
#pragma unroll
    for (int j = 0; j < 8; ++j) {
        aa[0][j] = __expf(aa[0][j] - m0); s0 += aa[0][j];
        aa[1][j] = __expf(aa[1][j] - m1); s1 += aa[1][j];
    }
#pragma unroll
    for (int mask = 1; mask < 32; mask <<= 1) {
        s0 += __shfl_xor(s0, mask, 32);
        s1 += __shfl_xor(s1, mask, 32);
    }
    const float rs0 = 1.f / s0, rs1 = 1.f / s1;
#pragma unroll
    for (int j = 0; j < 8; ++j) {
        const int cc = j >> 1, k2 = j & 1;
        const int skey = cc * 64 + kg + 32 * k2;
        af_lds[qg * 2 + 0][skey] = aa[0][j] * rs0;
        af_lds[qg * 2 + 1][skey] = aa[1][j] * rs1;
    }

    // ---- PV: bf[d,w] = sum_s af[d,s] * vf[s,w] ----
    const int qi = tid >> 4;           // 0..15
    const int wg = tid & 15;           // 0..15 -> w = wg*4..wg*4+3
    float4 acc = make_float4(0.f, 0.f, 0.f, 0.f);

    for (int cc = 0; cc < 4; ++cc) {
        __syncthreads();               // af complete (cc=0) / prev readers done
        {
            const int row = tid >> 2;
            const int c0  = (tid & 3) * 16;
            const float* vp = vf + ((b * NH + h) * NT + cc * 64 + row) * DM + c0;
#pragma unroll
            for (int i = 0; i < 4; ++i) {
                const float4 v = *reinterpret_cast<const float4*>(vp + i * 4);
                *reinterpret_cast<float4*>(&vfs[row][c0 + i * 4]) = v;
            }
        }
        __syncthreads();
#pragma unroll
        for (int s = 0; s < 64; ++s) {
            const float a = af_lds[qi][cc * 64 + s];
            const float4 v = *reinterpret_cast<const float4*>(&vfs[s][wg * 4]);
            acc.x += a * v.x; acc.y += a * v.y; acc.z += a * v.z; acc.w += a * v.w;
        }
    }
    float* op = bf + ((b * NH + h) * NT + qt * 16 + qi) * DM + wg * 4;
    *reinterpret_cast<float4*>(op) = acc;
}

// ---------------------------------------------------------------------------
// Kernel 3: b = sum_h bf; y = b*sigmoid(1.702b); out = x + y @ fanin_w.T + bias
// 64 blocks x 16 tokens, 256 threads.
// ---------------------------------------------------------------------------
__global__ __launch_bounds__(256) void k_out(const float* __restrict__ x,
                                             const float* __restrict__ bf,
                                             const float* __restrict__ fanin_w,
                                             const float* __restrict__ fanin_b,
                                             float* __restrict__ out)
{
    __shared__ float fw[64][65];       // +1 pad: w-major reads spread banks
    __shared__ float ys[16][64];

    const int tid  = threadIdx.x;
    const int tok0 = blockIdx.x * 16;

    // stage fanin_w (4096 floats)
    for (int i = tid * 4; i < 4096; i += 1024) {
        const float4 v = *reinterpret_cast<const float4*>(fanin_w + i);
        const int row = i >> 6, c = i & 63;
        fw[row][c + 0] = v.x; fw[row][c + 1] = v.y;
        fw[row][c + 2] = v.z; fw[row][c + 3] = v.w;
    }
    // h-sum + SiLU(1.702)
    for (int idx = tid; idx < 16 * 64; idx += 256) {
        const int t = idx >> 6, c = idx & 63;
        const int g = tok0 + t, b = g >> 8, tt = g & 255;
        float s = 0.f;
#pragma unroll
        for (int h = 0; h < NH; ++h)
            s += bf[((b * NH + h) * NT + tt) * DM + c];
        ys[t][c] = s * (1.f / (1.f + __expf(-1.702f * s)));
    }
    __syncthreads();
    // out = x + ys @ fw.T + bias
    for (int idx = tid; idx < 16 * 64; idx += 256) {
        const int t = idx >> 6, w = idx & 63;
        float acc = fanin_b[w];
#pragma unroll
        for (int c = 0; c < 64; ++c)
            acc += ys[t][c] * fw[w][c];
        const int g = tok0 + t;
        out[g * DM + w] = x[g * DM + w] + acc;
    }
}

// ---------------------------------------------------------------------------
extern "C" void kernel_launch(void* const* d_in, const int* in_sizes, int n_in,
                              void* d_out, int out_size, void* d_ws, size_t ws_size,
                              hipStream_t stream) {
    const float* x       = (const float*)d_in[0];
    const float* wk      = (const float*)d_in[1];
    const float* wqv_w   = (const float*)d_in[2];
    const float* wqv_b   = (const float*)d_in[3];
    const float* fanin_w = (const float*)d_in[4];
    const float* fanin_b = (const float*)d_in[5];
    float* out = (float*)d_out;

    float* ws  = (float*)d_ws;
    float* q_s = ws;                   // [4][4][256][64] = 262144 floats
    float* vfw = ws + 262144;          // [4][4][256][64]
    float* bfw = ws + 524288;          // [4][4][256][64]  (3 MB total)

    hipLaunchKernelGGL(k_proj, dim3(128),     dim3(256), 0, stream,
                       x, wk, wqv_w, wqv_b, q_s, vfw);
    hipLaunchKernelGGL(k_attn, dim3(16, 16),  dim3(256), 0, stream,
                       x, wk, q_s, vfw, bfw);
    hipLaunchKernelGGL(k_out,  dim3(64),      dim3(256), 0, stream,
                       x, bfw, fanin_w, fanin_b, out);
}

// Round 2
// 100.836 us; speedup vs baseline: 1.0524x; 1.0524x over previous
//
#include <hip/hip_runtime.h>

#define NT 256
#define DM 64
#define NH 4

// ---------------------------------------------------------------------------
// Kernel 1: fused QV projection. grid 256 x 256 thr, 4 tokens/block.
// Thread r computes output rows r (q, pre-scaled by wk) and r+256 (vf) for
// its block's 4 tokens. Weights streamed from L2 (no LDS staging: the whole
// working set is L2-resident; staging was pure overhead).
// ---------------------------------------------------------------------------
__global__ __launch_bounds__(256) void k_proj(const float* __restrict__ x,
                                              const float* __restrict__ wk,
                                              const float* __restrict__ wqv_w,
                                              const float* __restrict__ wqv_b,
                                              float* __restrict__ q_s,
                                              float* __restrict__ vf)
{
    __shared__ float xs[4 * DM];                       // 1 KB
    const int tid  = threadIdx.x;
    const int tok0 = blockIdx.x * 4;

    if (tid < 64)
        reinterpret_cast<float4*>(xs)[tid] =
            reinterpret_cast<const float4*>(x + tok0 * DM)[tid];
    __syncthreads();

    const float4* wr0 = reinterpret_cast<const float4*>(wqv_w + tid * DM);
    const float4* wr1 = reinterpret_cast<const float4*>(wqv_w + (tid + 256) * DM);
    float a0[4] = {0.f, 0.f, 0.f, 0.f};
    float a1[4] = {0.f, 0.f, 0.f, 0.f};

#pragma unroll
    for (int c4 = 0; c4 < 16; ++c4) {
        const float4 wa = wr0[c4];
        const float4 wb = wr1[c4];
#pragma unroll
        for (int t = 0; t < 4; ++t) {
            const float4 xv = reinterpret_cast<const float4*>(xs + t * DM)[c4];
            a0[t] += xv.x * wa.x + xv.y * wa.y + xv.z * wa.z + xv.w * wa.w;
            a1[t] += xv.x * wb.x + xv.y * wb.y + xv.z * wb.z + xv.w * wb.w;
        }
    }

    const int h = tid >> 6, w = tid & 63;
    const float ba = wqv_b[tid];
    const float bb = wqv_b[tid + 256];
    const float kw = wk[h * DM + w];
#pragma unroll
    for (int t = 0; t < 4; ++t) {
        const int g = tok0 + t, b = g >> 8, tt = g & 255;
        const int o = ((b * NH + h) * NT + tt) * DM + w;
        q_s[o] = (a0[t] + ba) * kw;
        vf[o]  =  a1[t] + bb;
    }
}

// ---------------------------------------------------------------------------
// Kernel 2: L1-distance attention. grid (16 qtile, 16 bh) x 256 thr.
//  dist[s,q] = sum_w |q_s[q,w] - x[s,w]*wk[h,w]| * 0.125
//  af = softmax_s(-huber(dist)); bf[q,w] = sum_s af[s,q]*vf[s,w]
// Distance: 2 queries/thread, float2 LDS reads (pad 66 -> 2-way = free).
// PV: 4q x 4w x 64s per thread + partial reduce (vfs read once per wave).
// ---------------------------------------------------------------------------
#define KS_LD 66
#define AF_LD 258

__global__ __launch_bounds__(256) void k_attn(const float* __restrict__ x,
                                              const float* __restrict__ wk,
                                              const float* __restrict__ q_s,
                                              const float* __restrict__ vf,
                                              float* __restrict__ bf)
{
    __shared__ float ks[64 * KS_LD];       // 16.5 KB
    __shared__ float af[16 * AF_LD];       // 16.1 KB (pad 258: PV reads conflict-free)
    __shared__ float vfs[NT * DM];         // 64 KB (linear: stage + s-uniform reads = conflict-free)
    __shared__ float part[4 * 16 * DM];    // 16 KB partial PV sums

    const int tid = threadIdx.x;
    const int qt  = blockIdx.x;            // query tile (16 queries)
    const int bh  = blockIdx.y;
    const int b   = bh >> 2, h = bh & 3;
    const int qg  = tid >> 5;              // 0..7: owns queries 2qg, 2qg+1
    const int kg  = tid & 31;

    // ---- queries into registers ----
    float q0[DM], q1[DM];
    {
        const float4* p0 = reinterpret_cast<const float4*>(
            q_s + ((b * NH + h) * NT + qt * 16 + qg * 2) * DM);
        const float4* p1 = p0 + 16;
#pragma unroll
        for (int i = 0; i < 16; ++i) {
            const float4 u = p0[i];
            q0[4*i] = u.x; q0[4*i+1] = u.y; q0[4*i+2] = u.z; q0[4*i+3] = u.w;
            const float4 v = p1[i];
            q1[4*i] = v.x; q1[4*i+1] = v.y; q1[4*i+2] = v.z; q1[4*i+3] = v.w;
        }
    }

    const float4* wkr = reinterpret_cast<const float4*>(wk + h * DM);

    // ---- distance over 4 chunks of 64 keys ----
    float dacc[2][8];
#pragma unroll
    for (int j = 0; j < 8; ++j) { dacc[0][j] = 0.f; dacc[1][j] = 0.f; }

    for (int cc = 0; cc < 4; ++cc) {
        __syncthreads();
        {   // stage ks[row][c] = x[b][cc*64+row][c] * wk[h][c]
            const int row = tid >> 2, c0 = (tid & 3) * 16;
            const float4* xp = reinterpret_cast<const float4*>(
                x + ((b * NT) + cc * 64 + row) * DM + c0);
            float* kp = ks + row * KS_LD + c0;
#pragma unroll
            for (int i = 0; i < 4; ++i) {
                const float4 v  = xp[i];
                const float4 wv = wkr[(c0 >> 2) + i];
                reinterpret_cast<float2*>(kp)[2*i]     = make_float2(v.x * wv.x, v.y * wv.y);
                reinterpret_cast<float2*>(kp)[2*i + 1] = make_float2(v.z * wv.z, v.w * wv.w);
            }
        }
        __syncthreads();
#pragma unroll
        for (int k2 = 0; k2 < 2; ++k2) {
            const float2* kp = reinterpret_cast<const float2*>(ks + (kg + 32 * k2) * KS_LD);
            float d0 = 0.f, d1 = 0.f;
#pragma unroll
            for (int c2 = 0; c2 < 32; ++c2) {
                const float2 kv = kp[c2];
                d0 += fabsf(q0[2*c2] - kv.x) + fabsf(q0[2*c2+1] - kv.y);
                d1 += fabsf(q1[2*c2] - kv.x) + fabsf(q1[2*c2+1] - kv.y);
            }
            dacc[0][cc * 2 + k2] = d0;
            dacc[1][cc * 2 + k2] = d1;
        }
    }

    // ---- stage all vf rows for this (b,h): 64 KB, linear ----
    {
        const float4* vp = reinterpret_cast<const float4*>(vf + (b * NH + h) * NT * DM);
#pragma unroll
        for (int it = 0; it < 16; ++it) {
            const int qidx = it * 256 + tid;
            reinterpret_cast<float4*>(vfs)[qidx] = vp[qidx];
        }
    }

    // ---- huber + softmax over 256 keys ----
    const float delta = 0.2f;
    float aa0[8], aa1[8];
    float m0 = -1e30f, m1 = -1e30f;
#pragma unroll
    for (int j = 0; j < 8; ++j) {
        float d  = dacc[0][j] * 0.125f;
        float hb = (d < delta) ? 0.5f * d * d : delta * (d - 0.5f * delta);
        aa0[j] = -hb; m0 = fmaxf(m0, aa0[j]);
        d  = dacc[1][j] * 0.125f;
        hb = (d < delta) ? 0.5f * d * d : delta * (d - 0.5f * delta);
        aa1[j] = -hb; m1 = fmaxf(m1, aa1[j]);
    }
#pragma unroll
    for (int mask = 1; mask < 32; mask <<= 1) {
        m0 = fmaxf(m0, __shfl_xor(m0, mask, 32));
        m1 = fmaxf(m1, __shfl_xor(m1, mask, 32));
    }
    float s0 = 0.f, s1 = 0.f;
#pragma unroll
    for (int j = 0; j < 8; ++j) {
        aa0[j] = __expf(aa0[j] - m0); s0 += aa0[j];
        aa1[j] = __expf(aa1[j] - m1); s1 += aa1[j];
    }
#pragma unroll
    for (int mask = 1; mask < 32; mask <<= 1) {
        s0 += __shfl_xor(s0, mask, 32);
        s1 += __shfl_xor(s1, mask, 32);
    }
    const float rs0 = 1.f / s0, rs1 = 1.f / s1;
#pragma unroll
    for (int j = 0; j < 8; ++j) {
        const int skey = (j >> 1) * 64 + (j & 1) * 32 + kg;
        af[(qg * 2 + 0) * AF_LD + skey] = aa0[j] * rs0;
        af[(qg * 2 + 1) * AF_LD + skey] = aa1[j] * rs1;
    }
    __syncthreads();   // af + vfs ready

    // ---- PV: thread = (wq 0..15, qg4 0..3, sr 0..3); 4q x 4w x 64s ----
    {
        const int wq  = tid & 15;
        const int qg4 = (tid >> 4) & 3;
        const int sr  = tid >> 6;

        float4 acc0 = {0,0,0,0}, acc1 = {0,0,0,0}, acc2 = {0,0,0,0}, acc3 = {0,0,0,0};
        const float* afb = af + (qg4 * 4) * AF_LD + sr * 64;
        const float* vb  = vfs + (sr * 64) * DM + wq * 4;
#pragma unroll
        for (int s = 0; s < 64; ++s) {
            const float4 v = *reinterpret_cast<const float4*>(vb + s * DM);
            const float a0 = afb[0 * AF_LD + s];
            const float a1 = afb[1 * AF_LD + s];
            const float a2 = afb[2 * AF_LD + s];
            const float a3 = afb[3 * AF_LD + s];
            acc0.x += a0 * v.x; acc0.y += a0 * v.y; acc0.z += a0 * v.z; acc0.w += a0 * v.w;
            acc1.x += a1 * v.x; acc1.y += a1 * v.y; acc1.z += a1 * v.z; acc1.w += a1 * v.w;
            acc2.x += a2 * v.x; acc2.y += a2 * v.y; acc2.z += a2 * v.z; acc2.w += a2 * v.w;
            acc3.x += a3 * v.x; acc3.y += a3 * v.y; acc3.z += a3 * v.z; acc3.w += a3 * v.w;
        }
        float* pp = part + (sr * 16 + qg4 * 4) * DM + wq * 4;
        *reinterpret_cast<float4*>(pp + 0 * DM) = acc0;
        *reinterpret_cast<float4*>(pp + 1 * DM) = acc1;
        *reinterpret_cast<float4*>(pp + 2 * DM) = acc2;
        *reinterpret_cast<float4*>(pp + 3 * DM) = acc3;
    }
    __syncthreads();

    // ---- reduce partials over sr, write bf ----
    {
        const int q = tid >> 4, w4 = tid & 15;
        const float* pp = part + q * DM + w4 * 4;
        float4 r0 = *reinterpret_cast<const float4*>(pp);
        const float4 r1 = *reinterpret_cast<const float4*>(pp + 16 * DM);
        const float4 r2 = *reinterpret_cast<const float4*>(pp + 32 * DM);
        const float4 r3 = *reinterpret_cast<const float4*>(pp + 48 * DM);
        r0.x += r1.x + r2.x + r3.x;
        r0.y += r1.y + r2.y + r3.y;
        r0.z += r1.z + r2.z + r3.z;
        r0.w += r1.w + r2.w + r3.w;
        float* op = bf + ((b * NH + h) * NT + qt * 16 + q) * DM + w4 * 4;
        *reinterpret_cast<float4*>(op) = r0;
    }
}

// ---------------------------------------------------------------------------
// Kernel 3: b = sum_h bf; y = silu_1.702(b); out = x + y @ fanin_w.T + bias.
// grid 256 x 256 thr, 4 tokens/block.
// ---------------------------------------------------------------------------
__global__ __launch_bounds__(256) void k_out(const float* __restrict__ x,
                                             const float* __restrict__ bf,
                                             const float* __restrict__ fanin_w,
                                             const float* __restrict__ fanin_b,
                                             float* __restrict__ out)
{
    __shared__ float fw[64 * 68];          // 17.4 KB (pad 68: b128-aligned rows)
    __shared__ float ys[4 * DM];

    const int tid  = threadIdx.x;
    const int tok0 = blockIdx.x * 4;

#pragma unroll
    for (int it = 0; it < 4; ++it) {
        const int qidx = it * 256 + tid;
        const int row = qidx >> 4, cq = qidx & 15;
        *reinterpret_cast<float4*>(fw + row * 68 + cq * 4) =
            reinterpret_cast<const float4*>(fanin_w)[qidx];
    }
    {   // h-sum + SiLU(1.702): thread -> (t, c)
        const int t = tid >> 6, c = tid & 63;
        const int g = tok0 + t, b = g >> 8, tt = g & 255;
        float s = 0.f;
#pragma unroll
        for (int hh = 0; hh < NH; ++hh)
            s += bf[((b * NH + hh) * NT + tt) * DM + c];
        ys[t * DM + c] = s / (1.f + __expf(-1.702f * s));
    }
    __syncthreads();
    {   // out = x + ys @ fw.T + bias: thread -> (t, w)
        const int t = tid >> 6, w = tid & 63;
        float acc = fanin_b[w];
        const float* yr = ys + t * DM;
        const float* fr = fw + w * 68;
#pragma unroll
        for (int c4 = 0; c4 < 16; ++c4) {
            const float4 yv = *reinterpret_cast<const float4*>(yr + c4 * 4);
            const float4 fv = *reinterpret_cast<const float4*>(fr + c4 * 4);
            acc += yv.x * fv.x + yv.y * fv.y + yv.z * fv.z + yv.w * fv.w;
        }
        const int g = tok0 + t;
        out[g * DM + w] = x[g * DM + w] + acc;
    }
}

// ---------------------------------------------------------------------------
extern "C" void kernel_launch(void* const* d_in, const int* in_sizes, int n_in,
                              void* d_out, int out_size, void* d_ws, size_t ws_size,
                              hipStream_t stream) {
    const float* x       = (const float*)d_in[0];
    const float* wk      = (const float*)d_in[1];
    const float* wqv_w   = (const float*)d_in[2];
    const float* wqv_b   = (const float*)d_in[3];
    const float* fanin_w = (const float*)d_in[4];
    const float* fanin_b = (const float*)d_in[5];
    float* out = (float*)d_out;

    float* ws  = (float*)d_ws;
    float* q_s = ws;                   // [4][4][256][64]
    float* vfw = ws + 262144;
    float* bfw = ws + 524288;

    hipLaunchKernelGGL(k_proj, dim3(256),     dim3(256), 0, stream,
                       x, wk, wqv_w, wqv_b, q_s, vfw);
    hipLaunchKernelGGL(k_attn, dim3(16, 16),  dim3(256), 0, stream,
                       x, wk, q_s, vfw, bfw);
    hipLaunchKernelGGL(k_out,  dim3(256),     dim3(256), 0, stream,
                       x, bfw, fanin_w, fanin_b, out);
}